// Round 8
// baseline (1826.570 us; speedup 1.0000x reference)
//
#include <hip/hip_runtime.h>
#include <cstdint>
#include <cstddef>

// Problem constants: B=1024, S=512, F=18, H=64, O=15
#define B_SZ  1024
#define S_LEN 512
#define NH    64

typedef float f32x2 __attribute__((ext_vector_type(2)));
typedef float f32x4 __attribute__((ext_vector_type(4)));

__device__ __forceinline__ float sigmoid_f(float x) {
    return __fdividef(1.0f, 1.0f + __expf(-x));
}
__device__ __forceinline__ float tanh_f(float x) {
    return 1.0f - __fdividef(2.0f, __expf(2.0f * x) + 1.0f);
}
// v_pk_fma_f32: acc.xy += a.xy * b.xy (2 fp32 FMA / lane / instr)
__device__ __forceinline__ void pk_fma(f32x2& acc, f32x2 a, f32x2 b) {
    asm("v_pk_fma_f32 %0, %1, %2, %0" : "+v"(acc) : "v"(a), "v"(b));
}
// x += (x from lane^XOR) via DPP quad_perm (VALU pipe, NOT the LDS pipe).
// 0xB1 = [1,0,3,2] = xor1; 0x4E = [2,3,0,1] = xor2.
template<int CTRL>
__device__ __forceinline__ float dpp_add(float x) {
    int s = __builtin_amdgcn_update_dpp(0, __float_as_int(x), CTRL, 0xF, 0xF, true);
    return x + __int_as_float(s);
}

// LSTM scan, register-gate-blocked, weights PINNED in VGPRs.
//   512 threads, R=2 batch rows per block, grid = 512 blocks (2/CU, all
//   1024 rows resident). Thread t -> (gg = t>>3, kc = t&7): owns 4 gate
//   rows g = 4*gg+j (j=0..3) on K-chunk kc (CH = KP/8 floats of [x|h|pad]).
//   Weights: 4*CH floats in VGPRs, kept resident via keepalive asm each
//   iteration (without it the compiler sinks the loads into the loop —
//   observed VGPR=88 < weight count in round 5).
//   Per step: phase A: NB ds_read_b128 per row (bank-staggered broadcast,
//   conflict-free) -> 4*CH FMAs/row via pk_fma -> DPP quad butterfly ->
//   ONE partial per row to g_part[r][t] (lane-contiguous: gate 4gg+(kc&3),
//   quad-half kc>>2 lands at word 8gg+4(kc>>2)+(kc&3) == t).
//   phase B: threads t<128 (waves 0-1): finisher for row r=t>>6, feature
//   jj=t&63: reads 8 partials (128c + 8(jj>>2)+4h+(jj&3)), +bias,
//   activations, c/h update, h -> in_lds (+global). Threads [128,128+R*KIN):
//   commit x_{s+1} prefetched at phase-A start (T14 split).
template<int KIN>
__global__ __launch_bounds__(512, 4) void lstm_scan(
    const float* __restrict__ xin,    // [B][S][KIN]
    const float* __restrict__ W_ih,   // [256][KIN]
    const float* __restrict__ W_hh,   // [256][64]
    const float* __restrict__ b_ih,   // [256]
    const float* __restrict__ b_hh,   // [256]
    float* __restrict__ h_all,        // [B][S][64] or nullptr
    float* __restrict__ h_last)       // [B][64]    or nullptr
{
    constexpr int R     = 2;
    constexpr int K     = KIN + NH;            // 82 / 128
    constexpr int KP    = (K + 31) & ~31;      // 96 / 128
    constexpr int CH    = KP / 8;              // 12 / 16
    constexpr int STAG  = (CH % 8 == 0) ? 4 : 0;
    constexpr int CROW  = CH + STAG;           // 12 / 20 (chunk bases hit
    constexpr int NB    = CH / 4;              //  distinct banks mod 32)
    constexpr int ROWW  = 8 * CROW;            // words per input row

    __shared__ __align__(16) float in_lds[R][ROWW];
    __shared__ float g_part[R][512];

    const int t  = threadIdx.x;
    const int kc = t & 7;
    const int gg = t >> 3;                     // 0..63
    const int b0 = blockIdx.x * R;

    auto WPOS = [](int f) { return (f / CH) * CROW + (f % CH); };

    // ---- persistent weights: 4 gates x CH floats (f32x2 pairs) ----
    f32x2 w2[4][CH / 2];
    #pragma unroll
    for (int j = 0; j < 4; ++j) {
        const int g = 4 * gg + j;
        #pragma unroll
        for (int i = 0; i < CH; ++i) {
            const int k = kc * CH + i;
            float wv;
            if (k < KIN)    wv = W_ih[g * KIN + k];
            else if (k < K) wv = W_hh[g * NH + (k - KIN)];
            else            wv = 0.0f;
            w2[j][i >> 1][i & 1] = wv;
        }
    }

    // ---- finisher state (t < 128): biases + cell state ----
    float bias_i = 0, bias_f = 0, bias_g = 0, bias_o = 0, cst = 0.0f;
    if (t < R * NH) {
        const int jj = t & 63;
        bias_i = b_ih[0 * NH + jj] + b_hh[0 * NH + jj];
        bias_f = b_ih[1 * NH + jj] + b_hh[1 * NH + jj];
        bias_g = b_ih[2 * NH + jj] + b_hh[2 * NH + jj];
        bias_o = b_ih[3 * NH + jj] + b_hh[3 * NH + jj];
    }

    // ---- init: zero input rows (h0 = 0, pads stay 0), load x_0 ----
    for (int i = t; i < R * ROWW; i += 512) ((float*)in_lds)[i] = 0.0f;
    __syncthreads();
    if (t >= 128 && t < 128 + R * KIN) {
        const int xt = t - 128, r = xt / KIN, f = xt - (xt / KIN) * KIN;
        in_lds[r][WPOS(f)] = xin[(size_t)(b0 + r) * S_LEN * KIN + f];
    }
    __syncthreads();

    const int ib = kc * CROW;                  // this thread's chunk base

    for (int s = 0; s < S_LEN; ++s) {
        // -- pin weights resident across the loop --
        #pragma unroll
        for (int j = 0; j < 4; ++j)
            #pragma unroll
            for (int i = 0; i < CH / 2; ++i)
                asm volatile("" : "+v"(w2[j][i]));

        // -- issue x_{s+1} prefetch early (committed in phase B) --
        float xreg = 0.0f;
        if (t >= 128 && t < 128 + R * KIN && s + 1 < S_LEN) {
            const int xt = t - 128, r = xt / KIN, f = xt - (xt / KIN) * KIN;
            xreg = xin[(size_t)(b0 + r) * S_LEN * KIN + (size_t)(s + 1) * KIN + f];
        }

        // -- phase A: 4-gate x 2-row chunk dot --
        float a[R][4];
        #pragma unroll
        for (int r = 0; r < R; ++r) {
            f32x2 acc[4] = {};
            #pragma unroll
            for (int ii = 0; ii < NB; ++ii) {
                const f32x4 v = *reinterpret_cast<const f32x4*>(&in_lds[r][ib + 4 * ii]);
                const f32x2 vlo = {v.x, v.y};
                const f32x2 vhi = {v.z, v.w};
                #pragma unroll
                for (int j = 0; j < 4; ++j) {
                    pk_fma(acc[j], w2[j][2 * ii],     vlo);
                    pk_fma(acc[j], w2[j][2 * ii + 1], vhi);
                }
            }
            #pragma unroll
            for (int j = 0; j < 4; ++j) a[r][j] = acc[j].x + acc[j].y;
        }
        // per-quad butterfly (xor1 + xor2): lane holds quad-sum of its 4 gates
        #pragma unroll
        for (int r = 0; r < R; ++r) {
            #pragma unroll
            for (int j = 0; j < 4; ++j) a[r][j] = dpp_add<0xB1>(a[r][j]);
            #pragma unroll
            for (int j = 0; j < 4; ++j) a[r][j] = dpp_add<0x4E>(a[r][j]);
        }
        // publish ONE partial: gate 4gg+(kc&3), half kc>>2 -> word t
        {
            const int sel = kc & 3;
            #pragma unroll
            for (int r = 0; r < R; ++r) {
                const float v01 = (sel & 1) ? a[r][1] : a[r][0];
                const float v23 = (sel & 1) ? a[r][3] : a[r][2];
                g_part[r][t] = (sel & 2) ? v23 : v01;
            }
        }
        __syncthreads();

        // -- phase B --
        if (t < R * NH) {                      // waves 0-1: finisher
            const int r  = t >> 6;
            const int jj = t & 63;
            const int w8 = 8 * (jj >> 2) + (jj & 3);
            const float pi = g_part[r][0 * 128 + w8] + g_part[r][0 * 128 + w8 + 4] + bias_i;
            const float pf = g_part[r][1 * 128 + w8] + g_part[r][1 * 128 + w8 + 4] + bias_f;
            const float pg = g_part[r][2 * 128 + w8] + g_part[r][2 * 128 + w8 + 4] + bias_g;
            const float po = g_part[r][3 * 128 + w8] + g_part[r][3 * 128 + w8 + 4] + bias_o;
            const float iv = sigmoid_f(pi);
            const float fv = sigmoid_f(pf);
            const float gv = tanh_f(pg);
            const float ov = sigmoid_f(po);
            cst = fmaf(fv, cst, iv * gv);
            const float hv = ov * tanh_f(cst);
            in_lds[r][WPOS(KIN + jj)] = hv;    // h_prev for next step
            if (h_all)
                h_all[((size_t)(b0 + r) * S_LEN + s) * NH + jj] = hv;
            if (h_last && s == S_LEN - 1)
                h_last[(size_t)(b0 + r) * NH + jj] = hv;
        } else if (t < 128 + R * KIN) {        // waves 2-3: x commit
            if (s + 1 < S_LEN) {
                const int xt = t - 128, r = xt / KIN, f = xt - (xt / KIN) * KIN;
                in_lds[r][WPOS(f)] = xreg;
            }
        }
        __syncthreads();
    }
}

// BatchNorm statistics over the batch dim: one block per feature.
__global__ void bn_stats_kernel(const float* __restrict__ last,   // [B][64]
                                const float* __restrict__ gamma,  // [64]
                                const float* __restrict__ beta,   // [64]
                                float* __restrict__ scale,        // [64]
                                float* __restrict__ shift)        // [64]
{
    const int jf = blockIdx.x;
    const int t  = threadIdx.x;  // 256 threads
    float s1 = 0.0f, s2 = 0.0f;
    for (int b = t; b < B_SZ; b += 256) {
        const float v = last[b * NH + jf];
        s1 += v; s2 += v * v;
    }
    #pragma unroll
    for (int off = 32; off > 0; off >>= 1) {
        s1 += __shfl_down(s1, off, 64);
        s2 += __shfl_down(s2, off, 64);
    }
    __shared__ float ls1[4], ls2[4];
    if ((t & 63) == 0) { ls1[t >> 6] = s1; ls2[t >> 6] = s2; }
    __syncthreads();
    if (t == 0) {
        const float S1 = ls1[0] + ls1[1] + ls1[2] + ls1[3];
        const float S2 = ls2[0] + ls2[1] + ls2[2] + ls2[3];
        const float mean = S1 * (1.0f / B_SZ);
        const float var  = S2 * (1.0f / B_SZ) - mean * mean;
        const float sc   = gamma[jf] * rsqrtf(var + 1e-5f);
        scale[jf] = sc;
        shift[jf] = beta[jf] - mean * sc;
    }
}

// Classifier: out[b,o] = sum_j (last[b,j]*scale[j]+shift[j]) * W[o,j] + bias[o]
__global__ void cls_kernel(const float* __restrict__ last,   // [B][64]
                           const float* __restrict__ scale,  // [64]
                           const float* __restrict__ shift,  // [64]
                           const float* __restrict__ W,      // [15][64]
                           const float* __restrict__ bias,   // [15]
                           float* __restrict__ out)          // [B][15]
{
    const int t  = threadIdx.x;        // 256 = 16 rows x 16 cols
    const int o  = t & 15;
    const int ry = t >> 4;
    const int b  = blockIdx.x * 16 + ry;
    if (o >= 15) return;
    float acc = bias[o];
    #pragma unroll
    for (int jf = 0; jf < NH; ++jf) {
        const float nv = fmaf(last[b * NH + jf], scale[jf], shift[jf]);
        acc = fmaf(nv, W[o * NH + jf], acc);
    }
    out[b * 15 + o] = acc;
}

extern "C" void kernel_launch(void* const* d_in, const int* in_sizes, int n_in,
                              void* d_out, int out_size, void* d_ws, size_t ws_size,
                              hipStream_t stream) {
    const float* X      = (const float*)d_in[0];   // [1024][512][18]
    const float* W_ih0  = (const float*)d_in[1];   // [256][18]
    const float* W_hh0  = (const float*)d_in[2];   // [256][64]
    const float* b_ih0  = (const float*)d_in[3];
    const float* b_hh0  = (const float*)d_in[4];
    const float* W_ih1  = (const float*)d_in[5];   // [256][64]
    const float* W_hh1  = (const float*)d_in[6];   // [256][64]
    const float* b_ih1  = (const float*)d_in[7];
    const float* b_hh1  = (const float*)d_in[8];
    const float* gamma  = (const float*)d_in[9];
    const float* beta   = (const float*)d_in[10];
    const float* cls_W  = (const float*)d_in[11];  // [15][64]
    const float* cls_b  = (const float*)d_in[12];
    float* out = (float*)d_out;                    // [1024][15]

    // Workspace: h1 [B][S][64] f32 (128MB) + last [B][64] + scale/shift
    float* h1    = (float*)d_ws;
    float* last  = h1 + (size_t)B_SZ * S_LEN * NH;
    float* scale = last + (size_t)B_SZ * NH;
    float* shift = scale + NH;

    lstm_scan<18><<<B_SZ / 2, 512, 0, stream>>>(
        X, W_ih0, W_hh0, b_ih0, b_hh0, h1, nullptr);
    lstm_scan<64><<<B_SZ / 2, 512, 0, stream>>>(
        h1, W_ih1, W_hh1, b_ih1, b_hh1, nullptr, last);
    bn_stats_kernel<<<NH, 256, 0, stream>>>(last, gamma, beta, scale, shift);
    cls_kernel<<<B_SZ / 16, 256, 0, stream>>>(last, scale, shift, cls_W, cls_b, out);
}